// Round 1
// baseline (2197.835 us; speedup 1.0000x reference)
//
#include <hip/hip_runtime.h>
#include <hip/hip_bf16.h>
#include <math.h>

// Problem constants (match reference)
#define ND 16
#define ED 8
#define HD 5
#define NG 256
#define EPS_GN 1e-5f

// ---------------------------------------------------------------------------
// Edge pass 1: for each edge e:
//   e1 = W1e @ ea + b1e            (8 -> 16)
//   m  = relu(x[src] + e1)         (16)
//   p  = nn1_W @ m                 (16 -> 5)   [linear commutes with segsum]
//   atomicAdd(agg1p[dst], p)       (5 atomics)
// ---------------------------------------------------------------------------
__global__ __launch_bounds__(256) void edge_pass1(
    const float* __restrict__ ea, const int* __restrict__ ei,
    const float* __restrict__ x,
    const float* __restrict__ W1e, const float* __restrict__ b1e,
    const float* __restrict__ Wn1,
    float* __restrict__ agg1p, long E) {
  __shared__ float sW[ND * ED];   // 128
  __shared__ float sB[ND];        // 16
  __shared__ float sP[HD * ND];   // 80
  int tid = threadIdx.x;
  if (tid < ND * ED) sW[tid] = W1e[tid];
  if (tid < ND) sB[tid] = b1e[tid];
  if (tid < HD * ND) sP[tid] = Wn1[tid];
  __syncthreads();

  const float4* ea4 = reinterpret_cast<const float4*>(ea);
  const int* src = ei;
  const int* dst = ei + E;
  long idx = (long)blockIdx.x * blockDim.x + tid;
  long stride = (long)gridDim.x * blockDim.x;

  for (long e = idx; e < E; e += stride) {
    float4 a0 = ea4[2 * e];
    float4 a1 = ea4[2 * e + 1];
    float av[ED] = {a0.x, a0.y, a0.z, a0.w, a1.x, a1.y, a1.z, a1.w};
    int s = src[e];
    int d = dst[e];
    const float4* xr = reinterpret_cast<const float4*>(x + (size_t)s * ND);
    float4 x0 = xr[0], x1 = xr[1], x2 = xr[2], x3 = xr[3];
    float xv[ND] = {x0.x, x0.y, x0.z, x0.w, x1.x, x1.y, x1.z, x1.w,
                    x2.x, x2.y, x2.z, x2.w, x3.x, x3.y, x3.z, x3.w};
    float p[HD] = {0.f, 0.f, 0.f, 0.f, 0.f};
#pragma unroll
    for (int j = 0; j < ND; ++j) {
      float m = sB[j];
#pragma unroll
      for (int k = 0; k < ED; ++k) m += sW[j * ED + k] * av[k];
      m = fmaxf(m + xv[j], 0.f);
#pragma unroll
      for (int q = 0; q < HD; ++q) p[q] += m * sP[q * ND + j];
    }
    float* ag = agg1p + (size_t)d * HD;
#pragma unroll
    for (int q = 0; q < HD; ++q) atomicAdd(ag + q, p[q]);
  }
}

// ---------------------------------------------------------------------------
// Node pass 1: h1[n] = (1+eps1) * (x[n] @ nn1_W^T) + agg1p[n] + nn1_b
// ---------------------------------------------------------------------------
__global__ __launch_bounds__(256) void node_pass1(
    const float* __restrict__ x, const float* __restrict__ agg1p,
    const float* __restrict__ Wn1, const float* __restrict__ bn1,
    const float* __restrict__ eps1p, float* __restrict__ h1, int N) {
  int n = blockIdx.x * blockDim.x + threadIdx.x;
  if (n >= N) return;
  float e1 = 1.0f + *eps1p;
  const float4* xr = reinterpret_cast<const float4*>(x + (size_t)n * ND);
  float4 x0 = xr[0], x1 = xr[1], x2 = xr[2], x3 = xr[3];
  float xv[ND] = {x0.x, x0.y, x0.z, x0.w, x1.x, x1.y, x1.z, x1.w,
                  x2.x, x2.y, x2.z, x2.w, x3.x, x3.y, x3.z, x3.w};
#pragma unroll
  for (int q = 0; q < HD; ++q) {
    float acc = 0.f;
#pragma unroll
    for (int j = 0; j < ND; ++j) acc += Wn1[q * ND + j] * xv[j];
    h1[(size_t)n * HD + q] = e1 * acc + agg1p[(size_t)n * HD + q] + bn1[q];
  }
}

// ---------------------------------------------------------------------------
// GraphNorm + ReLU. One block per graph. batch_idx is sorted, so each graph
// is a contiguous node range found by binary search. 3 passes over the range:
// mean, var, write.
// ---------------------------------------------------------------------------
__global__ __launch_bounds__(256) void graphnorm_pass(
    const float* __restrict__ h1, const int* __restrict__ batch,
    const float* __restrict__ w, const float* __restrict__ b,
    const float* __restrict__ ms, float* __restrict__ hn, int N) {
  int g = blockIdx.x;
  __shared__ int s_lo, s_hi;
  __shared__ float s_red[4][HD];
  __shared__ float s_mean[HD];   // mean_scale * mean
  __shared__ float s_scale[HD];  // weight * rsqrt(var + eps)
  if (threadIdx.x == 0) {
    int lo = 0, hi = N;
    while (lo < hi) { int mid = (lo + hi) >> 1; if (batch[mid] < g) lo = mid + 1; else hi = mid; }
    s_lo = lo;
    hi = N;
    while (lo < hi) { int mid = (lo + hi) >> 1; if (batch[mid] < g + 1) lo = mid + 1; else hi = mid; }
    s_hi = lo;
  }
  __syncthreads();
  int lo = s_lo, hi = s_hi;
  int cnt = hi - lo;
  float rc = 1.0f / fmaxf((float)cnt, 1.0f);
  int wid = threadIdx.x >> 6;
  int lane = threadIdx.x & 63;

  // pass 1: sums -> mean
  float acc[HD] = {0.f, 0.f, 0.f, 0.f, 0.f};
  for (int i = lo + threadIdx.x; i < hi; i += blockDim.x) {
#pragma unroll
    for (int q = 0; q < HD; ++q) acc[q] += h1[(size_t)i * HD + q];
  }
#pragma unroll
  for (int q = 0; q < HD; ++q)
    for (int off = 32; off > 0; off >>= 1) acc[q] += __shfl_down(acc[q], off);
  if (lane == 0)
#pragma unroll
    for (int q = 0; q < HD; ++q) s_red[wid][q] = acc[q];
  __syncthreads();
  if (threadIdx.x == 0) {
#pragma unroll
    for (int q = 0; q < HD; ++q)
      s_mean[q] = (s_red[0][q] + s_red[1][q] + s_red[2][q] + s_red[3][q]) * rc * ms[q];
  }
  __syncthreads();

  // pass 2: var
#pragma unroll
  for (int q = 0; q < HD; ++q) acc[q] = 0.f;
  for (int i = lo + threadIdx.x; i < hi; i += blockDim.x) {
#pragma unroll
    for (int q = 0; q < HD; ++q) {
      float s = h1[(size_t)i * HD + q] - s_mean[q];
      acc[q] += s * s;
    }
  }
#pragma unroll
  for (int q = 0; q < HD; ++q)
    for (int off = 32; off > 0; off >>= 1) acc[q] += __shfl_down(acc[q], off);
  if (lane == 0)
#pragma unroll
    for (int q = 0; q < HD; ++q) s_red[wid][q] = acc[q];
  __syncthreads();
  if (threadIdx.x == 0) {
#pragma unroll
    for (int q = 0; q < HD; ++q) {
      float var = (s_red[0][q] + s_red[1][q] + s_red[2][q] + s_red[3][q]) * rc;
      s_scale[q] = w[q] * rsqrtf(var + EPS_GN);
    }
  }
  __syncthreads();

  // pass 3: write relu(graphnorm)
  for (int i = lo + threadIdx.x; i < hi; i += blockDim.x) {
#pragma unroll
    for (int q = 0; q < HD; ++q) {
      float s = h1[(size_t)i * HD + q] - s_mean[q];
      hn[(size_t)i * HD + q] = fmaxf(s * s_scale[q] + b[q], 0.f);
    }
  }
}

// ---------------------------------------------------------------------------
// Edge pass 2: e2 = W2e @ ea + b2e (8->5); m = relu(hn[src] + e2);
// scalar = dot(nn2_W, m); atomicAdd(agg2s[dst], scalar)  (1 atomic/edge)
// ---------------------------------------------------------------------------
__global__ __launch_bounds__(256) void edge_pass2(
    const float* __restrict__ ea, const int* __restrict__ ei,
    const float* __restrict__ hn,
    const float* __restrict__ W2e, const float* __restrict__ b2e,
    const float* __restrict__ Wn2,
    float* __restrict__ agg2s, long E) {
  __shared__ float sW[HD * ED];  // 40
  __shared__ float sB[HD];       // 5
  __shared__ float sP[HD];       // 5
  int tid = threadIdx.x;
  if (tid < HD * ED) sW[tid] = W2e[tid];
  if (tid < HD) sB[tid] = b2e[tid];
  if (tid < HD) sP[tid] = Wn2[tid];
  __syncthreads();

  const float4* ea4 = reinterpret_cast<const float4*>(ea);
  const int* src = ei;
  const int* dst = ei + E;
  long idx = (long)blockIdx.x * blockDim.x + tid;
  long stride = (long)gridDim.x * blockDim.x;

  for (long e = idx; e < E; e += stride) {
    float4 a0 = ea4[2 * e];
    float4 a1 = ea4[2 * e + 1];
    float av[ED] = {a0.x, a0.y, a0.z, a0.w, a1.x, a1.y, a1.z, a1.w};
    int s = src[e];
    int d = dst[e];
    const float* hr = hn + (size_t)s * HD;
    float acc = 0.f;
#pragma unroll
    for (int q = 0; q < HD; ++q) {
      float m = sB[q];
#pragma unroll
      for (int k = 0; k < ED; ++k) m += sW[q * ED + k] * av[k];
      m = fmaxf(m + hr[q], 0.f);
      acc += m * sP[q];
    }
    atomicAdd(agg2s + d, acc);
  }
}

// ---------------------------------------------------------------------------
// Node pass 2: out[n] = sigmoid( nn2_b + agg2s[n]
//                                + (1+eps2) * dot(nn2_W, hn[n]) )
// ---------------------------------------------------------------------------
__global__ __launch_bounds__(256) void node_pass2(
    const float* __restrict__ hn, const float* __restrict__ agg2s,
    const float* __restrict__ Wn2, const float* __restrict__ bn2,
    const float* __restrict__ eps2p, float* __restrict__ out, int N) {
  int n = blockIdx.x * blockDim.x + threadIdx.x;
  if (n >= N) return;
  float e2 = 1.0f + *eps2p;
  const float* hr = hn + (size_t)n * HD;
  float z = bn2[0] + agg2s[n];
#pragma unroll
  for (int q = 0; q < HD; ++q) z += Wn2[q] * e2 * hr[q];
  out[n] = 1.0f / (1.0f + expf(-z));
}

// ---------------------------------------------------------------------------
extern "C" void kernel_launch(void* const* d_in, const int* in_sizes, int n_in,
                              void* d_out, int out_size, void* d_ws, size_t ws_size,
                              hipStream_t stream) {
  const float* x       = (const float*)d_in[0];
  const int*   ei      = (const int*)d_in[1];
  const float* ea      = (const float*)d_in[2];
  const int*   batch   = (const int*)d_in[3];
  const float* eps1    = (const float*)d_in[4];
  const float* W1e     = (const float*)d_in[5];
  const float* b1e     = (const float*)d_in[6];
  const float* Wn1     = (const float*)d_in[7];
  const float* bn1     = (const float*)d_in[8];
  const float* gn_w    = (const float*)d_in[9];
  const float* gn_b    = (const float*)d_in[10];
  const float* gn_ms   = (const float*)d_in[11];
  const float* eps2    = (const float*)d_in[12];
  const float* W2e     = (const float*)d_in[13];
  const float* b2e     = (const float*)d_in[14];
  const float* Wn2     = (const float*)d_in[15];
  const float* bn2     = (const float*)d_in[16];

  const int  N = in_sizes[3];
  const long E = (long)in_sizes[2] / ED;

  // workspace layout (floats):
  //   [0,        N*5)  agg1p  (zeroed)
  //   [N*5,      N*6)  agg2s  (zeroed)
  //   [N*6,      N*11) h1
  //   [N*11,     N*16) hn
  float* ws     = (float*)d_ws;
  float* agg1p  = ws;
  float* agg2s  = ws + (size_t)N * 5;
  float* h1     = ws + (size_t)N * 6;
  float* hn     = ws + (size_t)N * 11;
  float* out    = (float*)d_out;

  hipMemsetAsync(ws, 0, (size_t)N * 6 * sizeof(float), stream);

  const int TB = 256;
  int edge_blocks = 4096;
  int node_blocks = (N + TB - 1) / TB;

  edge_pass1<<<edge_blocks, TB, 0, stream>>>(ea, ei, x, W1e, b1e, Wn1, agg1p, E);
  node_pass1<<<node_blocks, TB, 0, stream>>>(x, agg1p, Wn1, bn1, eps1, h1, N);
  graphnorm_pass<<<NG, TB, 0, stream>>>(h1, batch, gn_w, gn_b, gn_ms, hn, N);
  edge_pass2<<<edge_blocks, TB, 0, stream>>>(ea, ei, hn, W2e, b2e, Wn2, agg2s, E);
  node_pass2<<<node_blocks, TB, 0, stream>>>(hn, agg2s, Wn2, bn2, eps2, out, N);
}

// Round 2
// 1521.752 us; speedup vs baseline: 1.4443x; 1.4443x over previous
//
#include <hip/hip_runtime.h>
#include <hip/hip_bf16.h>
#include <math.h>

// Problem constants (match reference)
#define ND 16
#define ED 8
#define HD 5
#define NG 256
#define EPS_GN 1e-5f

#define BUCKET_SHIFT 7                 // 128 nodes per bucket
#define BUCKET_NODES 128
#define NB_MAX 1600                    // cap for static LDS (N<=204800)
#define NBLK 2048                      // chunks for hist/build partition

// ---------------------------------------------------------------------------
// HW float atomic wrapper (used only in fallback path)
// ---------------------------------------------------------------------------
__device__ inline void atomAdd(float* p, float v) {
#if __has_builtin(__builtin_amdgcn_flat_atomic_fadd_f32)
  __builtin_amdgcn_flat_atomic_fadd_f32(p, v);
#elif __has_builtin(__builtin_amdgcn_global_atomic_fadd_f32)
  __builtin_amdgcn_global_atomic_fadd_f32((__attribute__((address_space(1))) float*)p, v);
#else
  atomicAdd(p, v);
#endif
}

// ===========================================================================
// SORT PATH (no global float atomics)
// ===========================================================================

// --- 1. per-block bucket histogram --------------------------------------
__global__ __launch_bounds__(256) void hist_kernel(
    const int* __restrict__ dstp, int* __restrict__ offs,
    long E, int NB, long chunk) {
  __shared__ int sh[NB_MAX];
  int tid = threadIdx.x;
  for (int j = tid; j < NB; j += 256) sh[j] = 0;
  __syncthreads();
  long e0 = (long)blockIdx.x * chunk;
  long e1 = e0 + chunk; if (e1 > E) e1 = E;
  for (long e = e0 + tid; e < e1; e += 256)
    atomicAdd(&sh[dstp[e] >> BUCKET_SHIFT], 1);
  __syncthreads();
  size_t base = (size_t)blockIdx.x * NB;
  for (int j = tid; j < NB; j += 256) offs[base + j] = sh[j];
}

// --- 2a. per-bucket serial prefix over blocks + totals -------------------
__global__ void scanA(int* __restrict__ offs, int* __restrict__ btot,
                      int NB, int nblk) {
  int j = blockIdx.x * blockDim.x + threadIdx.x;
  if (j >= NB) return;
  int run = 0;
  for (int b = 0; b < nblk; ++b) {
    size_t idx = (size_t)b * NB + j;
    int t = offs[idx];
    offs[idx] = run;
    run += t;
  }
  btot[j] = run;
}

// --- 2b. exclusive scan of bucket totals (single block) ------------------
__global__ __launch_bounds__(256) void scanB(
    const int* __restrict__ btot, int* __restrict__ bbase, int NB) {
  __shared__ int tsum[256];
  int t = threadIdx.x;
  int loc[8];
  int s = 0;
#pragma unroll
  for (int i = 0; i < 8; ++i) {
    int idx = t * 8 + i;
    int v = (idx < NB) ? btot[idx] : 0;
    loc[i] = s;
    s += v;
  }
  tsum[t] = s;
  __syncthreads();
  for (int off = 1; off < 256; off <<= 1) {
    int v = (t >= off) ? tsum[t - off] : 0;
    __syncthreads();
    tsum[t] += v;
    __syncthreads();
  }
  int base = (t > 0) ? tsum[t - 1] : 0;
#pragma unroll
  for (int i = 0; i < 8; ++i) {
    int idx = t * 8 + i;
    if (idx < NB) bbase[idx] = base + loc[i];
  }
}

// --- 2c. add bucket bases to per-block offsets ---------------------------
__global__ void scanC(int* __restrict__ offs, const int* __restrict__ bbase,
                      int NB) {
  size_t base = (size_t)blockIdx.x * NB;
  for (int j = threadIdx.x; j < NB; j += blockDim.x)
    offs[base + j] += bbase[j];
}

// --- 3. streaming edge pass: compute p (pass1 proj) + c2, scatter record -
// record = 12 floats: {dst, src, p[0..4], c2[0..4]}
__global__ __launch_bounds__(256) void build_scatter(
    const float* __restrict__ ea, const int* __restrict__ srcp,
    const int* __restrict__ dstp, const float* __restrict__ x,
    const float* __restrict__ W1e, const float* __restrict__ b1e,
    const float* __restrict__ Wn1, const float* __restrict__ W2e,
    const float* __restrict__ b2e,
    const int* __restrict__ offs, float* __restrict__ rec,
    long E, int NB, long chunk) {
  __shared__ int cur[NB_MAX];
  __shared__ float swt[272];  // [0,128) W1e | [128,144) b1e | [144,224) Wn1
                              // [224,264) W2e | [264,269) b2e
  int tid = threadIdx.x;
  if (tid < 128) swt[tid] = W1e[tid];
  if (tid < 16) swt[128 + tid] = b1e[tid];
  if (tid < 80) swt[144 + tid] = Wn1[tid];
  if (tid < 40) swt[224 + tid] = W2e[tid];
  if (tid < 5) swt[264 + tid] = b2e[tid];
  size_t obase = (size_t)blockIdx.x * NB;
  for (int j = tid; j < NB; j += 256) cur[j] = offs[obase + j];
  __syncthreads();

  const float4* ea4 = reinterpret_cast<const float4*>(ea);
  float4* rec4 = reinterpret_cast<float4*>(rec);
  long e0 = (long)blockIdx.x * chunk;
  long e1 = e0 + chunk; if (e1 > E) e1 = E;

  for (long e = e0 + tid; e < e1; e += 256) {
    float4 a0 = ea4[2 * e];
    float4 a1 = ea4[2 * e + 1];
    float av[ED] = {a0.x, a0.y, a0.z, a0.w, a1.x, a1.y, a1.z, a1.w};
    int s = srcp[e];
    int d = dstp[e];
    const float4* xr = reinterpret_cast<const float4*>(x + (size_t)s * ND);
    float4 x0 = xr[0], x1 = xr[1], x2 = xr[2], x3 = xr[3];
    float xv[ND] = {x0.x, x0.y, x0.z, x0.w, x1.x, x1.y, x1.z, x1.w,
                    x2.x, x2.y, x2.z, x2.w, x3.x, x3.y, x3.z, x3.w};
    float p[HD] = {0.f, 0.f, 0.f, 0.f, 0.f};
#pragma unroll
    for (int j = 0; j < ND; ++j) {
      float m = swt[128 + j];
#pragma unroll
      for (int k = 0; k < ED; ++k) m += swt[j * ED + k] * av[k];
      m = fmaxf(m + xv[j], 0.f);
#pragma unroll
      for (int q = 0; q < HD; ++q) p[q] += m * swt[144 + q * ND + j];
    }
    float c2[HD];
#pragma unroll
    for (int q = 0; q < HD; ++q) {
      float m = swt[264 + q];
#pragma unroll
      for (int k = 0; k < ED; ++k) m += swt[224 + q * ED + k] * av[k];
      c2[q] = m;
    }
    int bkt = d >> BUCKET_SHIFT;
    int pos = atomicAdd(&cur[bkt], 1);
    float4* r = rec4 + (size_t)pos * 3;
    r[0] = make_float4(__uint_as_float((unsigned)d), __uint_as_float((unsigned)s), p[0], p[1]);
    r[1] = make_float4(p[2], p[3], p[4], c2[0]);
    r[2] = make_float4(c2[1], c2[2], c2[3], c2[4]);
  }
}

// --- 4. bucket reduce pass 1 (+ fused node pass 1) -----------------------
__global__ __launch_bounds__(256) void reduce1(
    const float* __restrict__ rec, const int* __restrict__ bbase,
    const int* __restrict__ btot, const float* __restrict__ x,
    const float* __restrict__ Wn1, const float* __restrict__ bn1,
    const float* __restrict__ eps1p, float* __restrict__ h1, int N) {
  __shared__ float acc[BUCKET_NODES * HD];  // 640
  __shared__ float sWn1[80];
  __shared__ float sbn1[HD];
  __shared__ float seps;
  int tid = threadIdx.x;
  int j = blockIdx.x;
  if (tid < 80) sWn1[tid] = Wn1[tid];
  if (tid < HD) sbn1[tid] = bn1[tid];
  if (tid == 0) seps = 1.0f + eps1p[0];
  for (int i = tid; i < BUCKET_NODES * HD; i += 256) acc[i] = 0.f;
  __syncthreads();

  int nbase = j << BUCKET_SHIFT;
  int lo = bbase[j], hi = lo + btot[j];
  const float4* rec4 = reinterpret_cast<const float4*>(rec);
  for (int i = lo + tid; i < hi; i += 256) {
    float4 w0 = rec4[(size_t)i * 3];
    float4 w1 = rec4[(size_t)i * 3 + 1];
    int dl = (int)__float_as_uint(w0.x) - nbase;
    atomicAdd(&acc[dl * HD + 0], w0.z);
    atomicAdd(&acc[dl * HD + 1], w0.w);
    atomicAdd(&acc[dl * HD + 2], w1.x);
    atomicAdd(&acc[dl * HD + 3], w1.y);
    atomicAdd(&acc[dl * HD + 4], w1.z);
  }
  __syncthreads();

  for (int t = tid; t < BUCKET_NODES * HD; t += 256) {
    int node = nbase + t / HD;
    int q = t - (t / HD) * HD;
    if (node < N) {
      const float* xr = x + (size_t)node * ND;
      float dot = 0.f;
#pragma unroll
      for (int k = 0; k < ND; ++k) dot += sWn1[q * ND + k] * xr[k];
      h1[(size_t)node * HD + q] = seps * dot + acc[t] + sbn1[q];
    }
  }
}

// --- 5. GraphNorm + ReLU (unchanged from R1; one block per graph) --------
__global__ __launch_bounds__(256) void graphnorm_pass(
    const float* __restrict__ h1, const int* __restrict__ batch,
    const float* __restrict__ w, const float* __restrict__ b,
    const float* __restrict__ ms, float* __restrict__ hn, int N) {
  int g = blockIdx.x;
  __shared__ int s_lo, s_hi;
  __shared__ float s_red[4][HD];
  __shared__ float s_mean[HD];
  __shared__ float s_scale[HD];
  if (threadIdx.x == 0) {
    int lo = 0, hi = N;
    while (lo < hi) { int mid = (lo + hi) >> 1; if (batch[mid] < g) lo = mid + 1; else hi = mid; }
    s_lo = lo;
    hi = N;
    while (lo < hi) { int mid = (lo + hi) >> 1; if (batch[mid] < g + 1) lo = mid + 1; else hi = mid; }
    s_hi = lo;
  }
  __syncthreads();
  int lo = s_lo, hi = s_hi;
  int cnt = hi - lo;
  float rc = 1.0f / fmaxf((float)cnt, 1.0f);
  int wid = threadIdx.x >> 6;
  int lane = threadIdx.x & 63;

  float acc[HD] = {0.f, 0.f, 0.f, 0.f, 0.f};
  for (int i = lo + threadIdx.x; i < hi; i += blockDim.x) {
#pragma unroll
    for (int q = 0; q < HD; ++q) acc[q] += h1[(size_t)i * HD + q];
  }
#pragma unroll
  for (int q = 0; q < HD; ++q)
    for (int off = 32; off > 0; off >>= 1) acc[q] += __shfl_down(acc[q], off);
  if (lane == 0)
#pragma unroll
    for (int q = 0; q < HD; ++q) s_red[wid][q] = acc[q];
  __syncthreads();
  if (threadIdx.x == 0) {
#pragma unroll
    for (int q = 0; q < HD; ++q)
      s_mean[q] = (s_red[0][q] + s_red[1][q] + s_red[2][q] + s_red[3][q]) * rc * ms[q];
  }
  __syncthreads();

#pragma unroll
  for (int q = 0; q < HD; ++q) acc[q] = 0.f;
  for (int i = lo + threadIdx.x; i < hi; i += blockDim.x) {
#pragma unroll
    for (int q = 0; q < HD; ++q) {
      float s = h1[(size_t)i * HD + q] - s_mean[q];
      acc[q] += s * s;
    }
  }
#pragma unroll
  for (int q = 0; q < HD; ++q)
    for (int off = 32; off > 0; off >>= 1) acc[q] += __shfl_down(acc[q], off);
  if (lane == 0)
#pragma unroll
    for (int q = 0; q < HD; ++q) s_red[wid][q] = acc[q];
  __syncthreads();
  if (threadIdx.x == 0) {
#pragma unroll
    for (int q = 0; q < HD; ++q) {
      float var = (s_red[0][q] + s_red[1][q] + s_red[2][q] + s_red[3][q]) * rc;
      s_scale[q] = w[q] * rsqrtf(var + EPS_GN);
    }
  }
  __syncthreads();

  for (int i = lo + threadIdx.x; i < hi; i += blockDim.x) {
#pragma unroll
    for (int q = 0; q < HD; ++q) {
      float s = h1[(size_t)i * HD + q] - s_mean[q];
      hn[(size_t)i * HD + q] = fmaxf(s * s_scale[q] + b[q], 0.f);
    }
  }
}

// --- 6. bucket reduce pass 2 (+ fused sigmoid epilogue) ------------------
__global__ __launch_bounds__(256) void reduce2(
    const float* __restrict__ rec, const int* __restrict__ bbase,
    const int* __restrict__ btot, const float* __restrict__ hn,
    const float* __restrict__ Wn2, const float* __restrict__ bn2,
    const float* __restrict__ eps2p, float* __restrict__ out, int N) {
  __shared__ float acc[BUCKET_NODES];
  __shared__ float sP[HD];
  __shared__ float sb, seps;
  int tid = threadIdx.x;
  int j = blockIdx.x;
  if (tid < HD) sP[tid] = Wn2[tid];
  if (tid == 0) { sb = bn2[0]; seps = 1.0f + eps2p[0]; }
  if (tid < BUCKET_NODES) acc[tid] = 0.f;
  __syncthreads();

  int nbase = j << BUCKET_SHIFT;
  int lo = bbase[j], hi = lo + btot[j];
  const float4* rec4 = reinterpret_cast<const float4*>(rec);
  for (int i = lo + tid; i < hi; i += 256) {
    float4 w0 = rec4[(size_t)i * 3];
    float4 w1 = rec4[(size_t)i * 3 + 1];
    float4 w2 = rec4[(size_t)i * 3 + 2];
    int d = (int)__float_as_uint(w0.x);
    int s = (int)__float_as_uint(w0.y);
    const float* hr = hn + (size_t)s * HD;
    float v = sP[0] * fmaxf(hr[0] + w1.w, 0.f)
            + sP[1] * fmaxf(hr[1] + w2.x, 0.f)
            + sP[2] * fmaxf(hr[2] + w2.y, 0.f)
            + sP[3] * fmaxf(hr[3] + w2.z, 0.f)
            + sP[4] * fmaxf(hr[4] + w2.w, 0.f);
    atomicAdd(&acc[d - nbase], v);
  }
  __syncthreads();

  if (tid < BUCKET_NODES) {
    int node = nbase + tid;
    if (node < N) {
      const float* hr = hn + (size_t)node * HD;
      float z = sb + acc[tid];
#pragma unroll
      for (int q = 0; q < HD; ++q) z += seps * sP[q] * hr[q];
      out[node] = 1.0f / (1.0f + expf(-z));
    }
  }
}

// ===========================================================================
// FALLBACK PATH (R1 structure, HW-fadd atomics) — used only if ws too small
// ===========================================================================
__global__ __launch_bounds__(256) void edge_pass1(
    const float* __restrict__ ea, const int* __restrict__ ei,
    const float* __restrict__ x,
    const float* __restrict__ W1e, const float* __restrict__ b1e,
    const float* __restrict__ Wn1,
    float* __restrict__ agg1p, long E) {
  __shared__ float sW[ND * ED];
  __shared__ float sB[ND];
  __shared__ float sP[HD * ND];
  int tid = threadIdx.x;
  if (tid < ND * ED) sW[tid] = W1e[tid];
  if (tid < ND) sB[tid] = b1e[tid];
  if (tid < HD * ND) sP[tid] = Wn1[tid];
  __syncthreads();
  const float4* ea4 = reinterpret_cast<const float4*>(ea);
  const int* src = ei;
  const int* dst = ei + E;
  long idx = (long)blockIdx.x * blockDim.x + tid;
  long stride = (long)gridDim.x * blockDim.x;
  for (long e = idx; e < E; e += stride) {
    float4 a0 = ea4[2 * e];
    float4 a1 = ea4[2 * e + 1];
    float av[ED] = {a0.x, a0.y, a0.z, a0.w, a1.x, a1.y, a1.z, a1.w};
    int s = src[e];
    int d = dst[e];
    const float4* xr = reinterpret_cast<const float4*>(x + (size_t)s * ND);
    float4 x0 = xr[0], x1 = xr[1], x2 = xr[2], x3 = xr[3];
    float xv[ND] = {x0.x, x0.y, x0.z, x0.w, x1.x, x1.y, x1.z, x1.w,
                    x2.x, x2.y, x2.z, x2.w, x3.x, x3.y, x3.z, x3.w};
    float p[HD] = {0.f, 0.f, 0.f, 0.f, 0.f};
#pragma unroll
    for (int j = 0; j < ND; ++j) {
      float m = sB[j];
#pragma unroll
      for (int k = 0; k < ED; ++k) m += sW[j * ED + k] * av[k];
      m = fmaxf(m + xv[j], 0.f);
#pragma unroll
      for (int q = 0; q < HD; ++q) p[q] += m * sP[q * ND + j];
    }
    float* ag = agg1p + (size_t)d * HD;
#pragma unroll
    for (int q = 0; q < HD; ++q) atomAdd(ag + q, p[q]);
  }
}

__global__ __launch_bounds__(256) void node_pass1(
    const float* __restrict__ x, const float* __restrict__ agg1p,
    const float* __restrict__ Wn1, const float* __restrict__ bn1,
    const float* __restrict__ eps1p, float* __restrict__ h1, int N) {
  int n = blockIdx.x * blockDim.x + threadIdx.x;
  if (n >= N) return;
  float e1 = 1.0f + *eps1p;
  const float4* xr = reinterpret_cast<const float4*>(x + (size_t)n * ND);
  float4 x0 = xr[0], x1 = xr[1], x2 = xr[2], x3 = xr[3];
  float xv[ND] = {x0.x, x0.y, x0.z, x0.w, x1.x, x1.y, x1.z, x1.w,
                  x2.x, x2.y, x2.z, x2.w, x3.x, x3.y, x3.z, x3.w};
#pragma unroll
  for (int q = 0; q < HD; ++q) {
    float acc = 0.f;
#pragma unroll
    for (int j = 0; j < ND; ++j) acc += Wn1[q * ND + j] * xv[j];
    h1[(size_t)n * HD + q] = e1 * acc + agg1p[(size_t)n * HD + q] + bn1[q];
  }
}

__global__ __launch_bounds__(256) void edge_pass2(
    const float* __restrict__ ea, const int* __restrict__ ei,
    const float* __restrict__ hn,
    const float* __restrict__ W2e, const float* __restrict__ b2e,
    const float* __restrict__ Wn2,
    float* __restrict__ agg2s, long E) {
  __shared__ float sW[HD * ED];
  __shared__ float sB[HD];
  __shared__ float sP[HD];
  int tid = threadIdx.x;
  if (tid < HD * ED) sW[tid] = W2e[tid];
  if (tid < HD) sB[tid] = b2e[tid];
  if (tid < HD) sP[tid] = Wn2[tid];
  __syncthreads();
  const float4* ea4 = reinterpret_cast<const float4*>(ea);
  const int* src = ei;
  const int* dst = ei + E;
  long idx = (long)blockIdx.x * blockDim.x + tid;
  long stride = (long)gridDim.x * blockDim.x;
  for (long e = idx; e < E; e += stride) {
    float4 a0 = ea4[2 * e];
    float4 a1 = ea4[2 * e + 1];
    float av[ED] = {a0.x, a0.y, a0.z, a0.w, a1.x, a1.y, a1.z, a1.w};
    int s = src[e];
    int d = dst[e];
    const float* hr = hn + (size_t)s * HD;
    float acc = 0.f;
#pragma unroll
    for (int q = 0; q < HD; ++q) {
      float m = sB[q];
#pragma unroll
      for (int k = 0; k < ED; ++k) m += sW[q * ED + k] * av[k];
      m = fmaxf(m + hr[q], 0.f);
      acc += m * sP[q];
    }
    atomAdd(agg2s + d, acc);
  }
}

__global__ __launch_bounds__(256) void node_pass2(
    const float* __restrict__ hn, const float* __restrict__ agg2s,
    const float* __restrict__ Wn2, const float* __restrict__ bn2,
    const float* __restrict__ eps2p, float* __restrict__ out, int N) {
  int n = blockIdx.x * blockDim.x + threadIdx.x;
  if (n >= N) return;
  float e2 = 1.0f + *eps2p;
  const float* hr = hn + (size_t)n * HD;
  float z = bn2[0] + agg2s[n];
#pragma unroll
  for (int q = 0; q < HD; ++q) z += Wn2[q] * e2 * hr[q];
  out[n] = 1.0f / (1.0f + expf(-z));
}

// ===========================================================================
extern "C" void kernel_launch(void* const* d_in, const int* in_sizes, int n_in,
                              void* d_out, int out_size, void* d_ws, size_t ws_size,
                              hipStream_t stream) {
  const float* x       = (const float*)d_in[0];
  const int*   ei      = (const int*)d_in[1];
  const float* ea      = (const float*)d_in[2];
  const int*   batch   = (const int*)d_in[3];
  const float* eps1    = (const float*)d_in[4];
  const float* W1e     = (const float*)d_in[5];
  const float* b1e     = (const float*)d_in[6];
  const float* Wn1     = (const float*)d_in[7];
  const float* bn1     = (const float*)d_in[8];
  const float* gn_w    = (const float*)d_in[9];
  const float* gn_b    = (const float*)d_in[10];
  const float* gn_ms   = (const float*)d_in[11];
  const float* eps2    = (const float*)d_in[12];
  const float* W2e     = (const float*)d_in[13];
  const float* b2e     = (const float*)d_in[14];
  const float* Wn2     = (const float*)d_in[15];
  const float* bn2     = (const float*)d_in[16];

  const int  N = in_sizes[3];
  const long E = (long)in_sizes[2] / ED;
  const int  NB = (N + BUCKET_NODES - 1) >> BUCKET_SHIFT;
  const size_t NBp = ((size_t)NB + 3) & ~(size_t)3;

  // sort-path workspace (float/int units)
  const size_t recF  = (size_t)E * 12;          // 48B records
  const size_t offsI = (size_t)NBLK * NB;
  const size_t need  = (recF + offsI + 2 * NBp + 10 * (size_t)N + 64) * 4;

  float* out = (float*)d_out;
  const int* srcp = ei;
  const int* dstp = ei + E;

  if (ws_size >= need && NB <= NB_MAX) {
    // ------------------------- SORT PATH -------------------------
    float* ws    = (float*)d_ws;
    float* rec   = ws;
    int*   offs  = (int*)(ws + recF);
    int*   btot  = (int*)(ws + recF + offsI);
    int*   bbase = (int*)(ws + recF + offsI + NBp);
    float* h1    = ws + recF + offsI + 2 * NBp;
    float* hn    = h1 + 5 * (size_t)N;

    const long chunk = (E + NBLK - 1) / NBLK;

    hist_kernel<<<NBLK, 256, 0, stream>>>(dstp, offs, E, NB, chunk);
    scanA<<<(NB + 255) / 256, 256, 0, stream>>>(offs, btot, NB, NBLK);
    scanB<<<1, 256, 0, stream>>>(btot, bbase, NB);
    scanC<<<NBLK, 256, 0, stream>>>(offs, bbase, NB);
    build_scatter<<<NBLK, 256, 0, stream>>>(ea, srcp, dstp, x,
                                            W1e, b1e, Wn1, W2e, b2e,
                                            offs, rec, E, NB, chunk);
    reduce1<<<NB, 256, 0, stream>>>(rec, bbase, btot, x, Wn1, bn1, eps1, h1, N);
    graphnorm_pass<<<NG, 256, 0, stream>>>(h1, batch, gn_w, gn_b, gn_ms, hn, N);
    reduce2<<<NB, 256, 0, stream>>>(rec, bbase, btot, hn, Wn2, bn2, eps2, out, N);
  } else {
    // ----------------------- FALLBACK PATH -----------------------
    float* ws     = (float*)d_ws;
    float* agg1p  = ws;
    float* agg2s  = ws + (size_t)N * 5;
    float* h1     = ws + (size_t)N * 6;
    float* hn     = ws + (size_t)N * 11;

    hipMemsetAsync(ws, 0, (size_t)N * 6 * sizeof(float), stream);

    const int TB = 256;
    int edge_blocks = 4096;
    int node_blocks = (N + TB - 1) / TB;

    edge_pass1<<<edge_blocks, TB, 0, stream>>>(ea, ei, x, W1e, b1e, Wn1, agg1p, E);
    node_pass1<<<node_blocks, TB, 0, stream>>>(x, agg1p, Wn1, bn1, eps1, h1, N);
    graphnorm_pass<<<NG, TB, 0, stream>>>(h1, batch, gn_w, gn_b, gn_ms, hn, N);
    edge_pass2<<<edge_blocks, TB, 0, stream>>>(ea, ei, hn, W2e, b2e, Wn2, agg2s, E);
    node_pass2<<<node_blocks, TB, 0, stream>>>(hn, agg2s, Wn2, bn2, eps2, out, N);
  }
}

// Round 3
// 1095.646 us; speedup vs baseline: 2.0060x; 1.3889x over previous
//
#include <hip/hip_runtime.h>
#include <hip/hip_bf16.h>
#include <math.h>

// Problem constants (match reference)
#define ND 16
#define ED 8
#define HD 5
#define NG 256
#define EPS_GN 1e-5f

#define BUCKET_SHIFT 7                 // 128 nodes per bucket
#define BUCKET_NODES 128
#define NB_MAX 1600                    // cap for static LDS (N<=204800)
#define NBLK 2048                      // chunks for hist/build partition
#define SCAN_PER (NBLK / 256)          // values per thread in scan_blocks

// ---------------------------------------------------------------------------
// HW float atomic wrapper (used only in fallback path)
// ---------------------------------------------------------------------------
__device__ inline void atomAdd(float* p, float v) {
#if __has_builtin(__builtin_amdgcn_flat_atomic_fadd_f32)
  __builtin_amdgcn_flat_atomic_fadd_f32(p, v);
#elif __has_builtin(__builtin_amdgcn_global_atomic_fadd_f32)
  __builtin_amdgcn_global_atomic_fadd_f32((__attribute__((address_space(1))) float*)p, v);
#else
  atomicAdd(p, v);
#endif
}

// ===========================================================================
// SORT PATH (no global float atomics)
// ===========================================================================

// --- 1. per-block bucket histogram --------------------------------------
__global__ __launch_bounds__(256) void hist_kernel(
    const int* __restrict__ dstp, int* __restrict__ offs,
    long E, int NB, long chunk) {
  __shared__ int sh[NB_MAX];
  int tid = threadIdx.x;
  for (int j = tid; j < NB; j += 256) sh[j] = 0;
  __syncthreads();
  long e0 = (long)blockIdx.x * chunk;
  long e1 = e0 + chunk; if (e1 > E) e1 = E;
  for (long e = e0 + tid; e < e1; e += 256)
    atomicAdd(&sh[dstp[e] >> BUCKET_SHIFT], 1);
  __syncthreads();
  size_t base = (size_t)blockIdx.x * NB;
  for (int j = tid; j < NB; j += 256) offs[base + j] = sh[j];
}

// --- 2a. PARALLEL per-bucket exclusive scan over blocks ------------------
// One 256-thread block per bucket j. Scans offs[b*NB+j] over b=0..NBLK-1,
// writes back RELATIVE exclusive offsets (no bucket base), btot[j] = total.
__global__ __launch_bounds__(256) void scan_blocks(
    int* __restrict__ offs, int* __restrict__ btot, int NB) {
  int j = blockIdx.x;
  int t = threadIdx.x;
  __shared__ int tsum[256];
  int loc[SCAN_PER];
  int s = 0;
#pragma unroll
  for (int i = 0; i < SCAN_PER; ++i) {
    int b = t * SCAN_PER + i;
    int v = offs[(size_t)b * NB + j];
    loc[i] = s;
    s += v;
  }
  tsum[t] = s;
  __syncthreads();
  for (int off = 1; off < 256; off <<= 1) {
    int v = (t >= off) ? tsum[t - off] : 0;
    __syncthreads();
    tsum[t] += v;
    __syncthreads();
  }
  int base = (t > 0) ? tsum[t - 1] : 0;
#pragma unroll
  for (int i = 0; i < SCAN_PER; ++i) {
    int b = t * SCAN_PER + i;
    offs[(size_t)b * NB + j] = base + loc[i];
  }
  if (t == 255) btot[j] = tsum[255];
}

// --- 2b. exclusive scan of bucket totals (single block) ------------------
__global__ __launch_bounds__(256) void scanB(
    const int* __restrict__ btot, int* __restrict__ bbase, int NB) {
  __shared__ int tsum[256];
  int t = threadIdx.x;
  int loc[8];
  int s = 0;
#pragma unroll
  for (int i = 0; i < 8; ++i) {
    int idx = t * 8 + i;
    int v = (idx < NB) ? btot[idx] : 0;
    loc[i] = s;
    s += v;
  }
  tsum[t] = s;
  __syncthreads();
  for (int off = 1; off < 256; off <<= 1) {
    int v = (t >= off) ? tsum[t - off] : 0;
    __syncthreads();
    tsum[t] += v;
    __syncthreads();
  }
  int base = (t > 0) ? tsum[t - 1] : 0;
#pragma unroll
  for (int i = 0; i < 8; ++i) {
    int idx = t * 8 + i;
    if (idx < NB) bbase[idx] = base + loc[i];
  }
}

// --- 3. streaming edge pass: compute p (pass1 proj) + c2, scatter record -
// record = 12 floats: {dst, src, p[0..4], c2[0..4]}
// Cursor init adds bbase[j] (absolute positions) — scanC eliminated.
__global__ __launch_bounds__(256) void build_scatter(
    const float* __restrict__ ea, const int* __restrict__ srcp,
    const int* __restrict__ dstp, const float* __restrict__ x,
    const float* __restrict__ W1e, const float* __restrict__ b1e,
    const float* __restrict__ Wn1, const float* __restrict__ W2e,
    const float* __restrict__ b2e,
    const int* __restrict__ offs, const int* __restrict__ bbase,
    float* __restrict__ rec,
    long E, int NB, long chunk) {
  __shared__ int cur[NB_MAX];
  __shared__ float swt[272];  // [0,128) W1e | [128,144) b1e | [144,224) Wn1
                              // [224,264) W2e | [264,269) b2e
  int tid = threadIdx.x;
  if (tid < 128) swt[tid] = W1e[tid];
  if (tid < 16) swt[128 + tid] = b1e[tid];
  if (tid < 80) swt[144 + tid] = Wn1[tid];
  if (tid < 40) swt[224 + tid] = W2e[tid];
  if (tid < 5) swt[264 + tid] = b2e[tid];
  size_t obase = (size_t)blockIdx.x * NB;
  for (int j = tid; j < NB; j += 256) cur[j] = offs[obase + j] + bbase[j];
  __syncthreads();

  const float4* ea4 = reinterpret_cast<const float4*>(ea);
  float4* rec4 = reinterpret_cast<float4*>(rec);
  long e0 = (long)blockIdx.x * chunk;
  long e1 = e0 + chunk; if (e1 > E) e1 = E;

  for (long e = e0 + tid; e < e1; e += 256) {
    float4 a0 = ea4[2 * e];
    float4 a1 = ea4[2 * e + 1];
    float av[ED] = {a0.x, a0.y, a0.z, a0.w, a1.x, a1.y, a1.z, a1.w};
    int s = srcp[e];
    int d = dstp[e];
    const float4* xr = reinterpret_cast<const float4*>(x + (size_t)s * ND);
    float4 x0 = xr[0], x1 = xr[1], x2 = xr[2], x3 = xr[3];
    float xv[ND] = {x0.x, x0.y, x0.z, x0.w, x1.x, x1.y, x1.z, x1.w,
                    x2.x, x2.y, x2.z, x2.w, x3.x, x3.y, x3.z, x3.w};
    float p[HD] = {0.f, 0.f, 0.f, 0.f, 0.f};
#pragma unroll
    for (int j = 0; j < ND; ++j) {
      float m = swt[128 + j];
#pragma unroll
      for (int k = 0; k < ED; ++k) m += swt[j * ED + k] * av[k];
      m = fmaxf(m + xv[j], 0.f);
#pragma unroll
      for (int q = 0; q < HD; ++q) p[q] += m * swt[144 + q * ND + j];
    }
    float c2[HD];
#pragma unroll
    for (int q = 0; q < HD; ++q) {
      float m = swt[264 + q];
#pragma unroll
      for (int k = 0; k < ED; ++k) m += swt[224 + q * ED + k] * av[k];
      c2[q] = m;
    }
    int bkt = d >> BUCKET_SHIFT;
    int pos = atomicAdd(&cur[bkt], 1);
    float4* r = rec4 + (size_t)pos * 3;
    r[0] = make_float4(__uint_as_float((unsigned)d), __uint_as_float((unsigned)s), p[0], p[1]);
    r[1] = make_float4(p[2], p[3], p[4], c2[0]);
    r[2] = make_float4(c2[1], c2[2], c2[3], c2[4]);
  }
}

// --- 4. bucket reduce pass 1 (+ fused node pass 1) -----------------------
__global__ __launch_bounds__(256) void reduce1(
    const float* __restrict__ rec, const int* __restrict__ bbase,
    const int* __restrict__ btot, const float* __restrict__ x,
    const float* __restrict__ Wn1, const float* __restrict__ bn1,
    const float* __restrict__ eps1p, float* __restrict__ h1, int N) {
  __shared__ float acc[BUCKET_NODES * HD];  // 640
  __shared__ float sWn1[80];
  __shared__ float sbn1[HD];
  __shared__ float seps;
  int tid = threadIdx.x;
  int j = blockIdx.x;
  if (tid < 80) sWn1[tid] = Wn1[tid];
  if (tid < HD) sbn1[tid] = bn1[tid];
  if (tid == 0) seps = 1.0f + eps1p[0];
  for (int i = tid; i < BUCKET_NODES * HD; i += 256) acc[i] = 0.f;
  __syncthreads();

  int nbase = j << BUCKET_SHIFT;
  int lo = bbase[j], hi = lo + btot[j];
  const float4* rec4 = reinterpret_cast<const float4*>(rec);
  for (int i = lo + tid; i < hi; i += 256) {
    float4 w0 = rec4[(size_t)i * 3];
    float4 w1 = rec4[(size_t)i * 3 + 1];
    int dl = (int)__float_as_uint(w0.x) - nbase;
    atomicAdd(&acc[dl * HD + 0], w0.z);
    atomicAdd(&acc[dl * HD + 1], w0.w);
    atomicAdd(&acc[dl * HD + 2], w1.x);
    atomicAdd(&acc[dl * HD + 3], w1.y);
    atomicAdd(&acc[dl * HD + 4], w1.z);
  }
  __syncthreads();

  for (int t = tid; t < BUCKET_NODES * HD; t += 256) {
    int node = nbase + t / HD;
    int q = t - (t / HD) * HD;
    if (node < N) {
      const float* xr = x + (size_t)node * ND;
      float dot = 0.f;
#pragma unroll
      for (int k = 0; k < ND; ++k) dot += sWn1[q * ND + k] * xr[k];
      h1[(size_t)node * HD + q] = seps * dot + acc[t] + sbn1[q];
    }
  }
}

// --- 5. GraphNorm + ReLU (one block per graph) ---------------------------
__global__ __launch_bounds__(256) void graphnorm_pass(
    const float* __restrict__ h1, const int* __restrict__ batch,
    const float* __restrict__ w, const float* __restrict__ b,
    const float* __restrict__ ms, float* __restrict__ hn, int N) {
  int g = blockIdx.x;
  __shared__ int s_lo, s_hi;
  __shared__ float s_red[4][HD];
  __shared__ float s_mean[HD];
  __shared__ float s_scale[HD];
  if (threadIdx.x == 0) {
    int lo = 0, hi = N;
    while (lo < hi) { int mid = (lo + hi) >> 1; if (batch[mid] < g) lo = mid + 1; else hi = mid; }
    s_lo = lo;
    hi = N;
    while (lo < hi) { int mid = (lo + hi) >> 1; if (batch[mid] < g + 1) lo = mid + 1; else hi = mid; }
    s_hi = lo;
  }
  __syncthreads();
  int lo = s_lo, hi = s_hi;
  int cnt = hi - lo;
  float rc = 1.0f / fmaxf((float)cnt, 1.0f);
  int wid = threadIdx.x >> 6;
  int lane = threadIdx.x & 63;

  float acc[HD] = {0.f, 0.f, 0.f, 0.f, 0.f};
  for (int i = lo + threadIdx.x; i < hi; i += blockDim.x) {
#pragma unroll
    for (int q = 0; q < HD; ++q) acc[q] += h1[(size_t)i * HD + q];
  }
#pragma unroll
  for (int q = 0; q < HD; ++q)
    for (int off = 32; off > 0; off >>= 1) acc[q] += __shfl_down(acc[q], off);
  if (lane == 0)
#pragma unroll
    for (int q = 0; q < HD; ++q) s_red[wid][q] = acc[q];
  __syncthreads();
  if (threadIdx.x == 0) {
#pragma unroll
    for (int q = 0; q < HD; ++q)
      s_mean[q] = (s_red[0][q] + s_red[1][q] + s_red[2][q] + s_red[3][q]) * rc * ms[q];
  }
  __syncthreads();

#pragma unroll
  for (int q = 0; q < HD; ++q) acc[q] = 0.f;
  for (int i = lo + threadIdx.x; i < hi; i += blockDim.x) {
#pragma unroll
    for (int q = 0; q < HD; ++q) {
      float s = h1[(size_t)i * HD + q] - s_mean[q];
      acc[q] += s * s;
    }
  }
#pragma unroll
  for (int q = 0; q < HD; ++q)
    for (int off = 32; off > 0; off >>= 1) acc[q] += __shfl_down(acc[q], off);
  if (lane == 0)
#pragma unroll
    for (int q = 0; q < HD; ++q) s_red[wid][q] = acc[q];
  __syncthreads();
  if (threadIdx.x == 0) {
#pragma unroll
    for (int q = 0; q < HD; ++q) {
      float var = (s_red[0][q] + s_red[1][q] + s_red[2][q] + s_red[3][q]) * rc;
      s_scale[q] = w[q] * rsqrtf(var + EPS_GN);
    }
  }
  __syncthreads();

  for (int i = lo + threadIdx.x; i < hi; i += blockDim.x) {
#pragma unroll
    for (int q = 0; q < HD; ++q) {
      float s = h1[(size_t)i * HD + q] - s_mean[q];
      hn[(size_t)i * HD + q] = fmaxf(s * s_scale[q] + b[q], 0.f);
    }
  }
}

// --- 6. bucket reduce pass 2 (+ fused sigmoid epilogue) ------------------
__global__ __launch_bounds__(256) void reduce2(
    const float* __restrict__ rec, const int* __restrict__ bbase,
    const int* __restrict__ btot, const float* __restrict__ hn,
    const float* __restrict__ Wn2, const float* __restrict__ bn2,
    const float* __restrict__ eps2p, float* __restrict__ out, int N) {
  __shared__ float acc[BUCKET_NODES];
  __shared__ float sP[HD];
  __shared__ float sb, seps;
  int tid = threadIdx.x;
  int j = blockIdx.x;
  if (tid < HD) sP[tid] = Wn2[tid];
  if (tid == 0) { sb = bn2[0]; seps = 1.0f + eps2p[0]; }
  if (tid < BUCKET_NODES) acc[tid] = 0.f;
  __syncthreads();

  int nbase = j << BUCKET_SHIFT;
  int lo = bbase[j], hi = lo + btot[j];
  const float4* rec4 = reinterpret_cast<const float4*>(rec);
  for (int i = lo + tid; i < hi; i += 256) {
    float4 w0 = rec4[(size_t)i * 3];
    float4 w1 = rec4[(size_t)i * 3 + 1];
    float4 w2 = rec4[(size_t)i * 3 + 2];
    int d = (int)__float_as_uint(w0.x);
    int s = (int)__float_as_uint(w0.y);
    const float* hr = hn + (size_t)s * HD;
    float v = sP[0] * fmaxf(hr[0] + w1.w, 0.f)
            + sP[1] * fmaxf(hr[1] + w2.x, 0.f)
            + sP[2] * fmaxf(hr[2] + w2.y, 0.f)
            + sP[3] * fmaxf(hr[3] + w2.z, 0.f)
            + sP[4] * fmaxf(hr[4] + w2.w, 0.f);
    atomicAdd(&acc[d - nbase], v);
  }
  __syncthreads();

  if (tid < BUCKET_NODES) {
    int node = nbase + tid;
    if (node < N) {
      const float* hr = hn + (size_t)node * HD;
      float z = sb + acc[tid];
#pragma unroll
      for (int q = 0; q < HD; ++q) z += seps * sP[q] * hr[q];
      out[node] = 1.0f / (1.0f + expf(-z));
    }
  }
}

// ===========================================================================
// FALLBACK PATH (R1 structure, HW-fadd atomics) — used only if ws too small
// ===========================================================================
__global__ __launch_bounds__(256) void edge_pass1(
    const float* __restrict__ ea, const int* __restrict__ ei,
    const float* __restrict__ x,
    const float* __restrict__ W1e, const float* __restrict__ b1e,
    const float* __restrict__ Wn1,
    float* __restrict__ agg1p, long E) {
  __shared__ float sW[ND * ED];
  __shared__ float sB[ND];
  __shared__ float sP[HD * ND];
  int tid = threadIdx.x;
  if (tid < ND * ED) sW[tid] = W1e[tid];
  if (tid < ND) sB[tid] = b1e[tid];
  if (tid < HD * ND) sP[tid] = Wn1[tid];
  __syncthreads();
  const float4* ea4 = reinterpret_cast<const float4*>(ea);
  const int* src = ei;
  const int* dst = ei + E;
  long idx = (long)blockIdx.x * blockDim.x + tid;
  long stride = (long)gridDim.x * blockDim.x;
  for (long e = idx; e < E; e += stride) {
    float4 a0 = ea4[2 * e];
    float4 a1 = ea4[2 * e + 1];
    float av[ED] = {a0.x, a0.y, a0.z, a0.w, a1.x, a1.y, a1.z, a1.w};
    int s = src[e];
    int d = dst[e];
    const float4* xr = reinterpret_cast<const float4*>(x + (size_t)s * ND);
    float4 x0 = xr[0], x1 = xr[1], x2 = xr[2], x3 = xr[3];
    float xv[ND] = {x0.x, x0.y, x0.z, x0.w, x1.x, x1.y, x1.z, x1.w,
                    x2.x, x2.y, x2.z, x2.w, x3.x, x3.y, x3.z, x3.w};
    float p[HD] = {0.f, 0.f, 0.f, 0.f, 0.f};
#pragma unroll
    for (int j = 0; j < ND; ++j) {
      float m = sB[j];
#pragma unroll
      for (int k = 0; k < ED; ++k) m += sW[j * ED + k] * av[k];
      m = fmaxf(m + xv[j], 0.f);
#pragma unroll
      for (int q = 0; q < HD; ++q) p[q] += m * sP[q * ND + j];
    }
    float* ag = agg1p + (size_t)d * HD;
#pragma unroll
    for (int q = 0; q < HD; ++q) atomAdd(ag + q, p[q]);
  }
}

__global__ __launch_bounds__(256) void node_pass1(
    const float* __restrict__ x, const float* __restrict__ agg1p,
    const float* __restrict__ Wn1, const float* __restrict__ bn1,
    const float* __restrict__ eps1p, float* __restrict__ h1, int N) {
  int n = blockIdx.x * blockDim.x + threadIdx.x;
  if (n >= N) return;
  float e1 = 1.0f + *eps1p;
  const float4* xr = reinterpret_cast<const float4*>(x + (size_t)n * ND);
  float4 x0 = xr[0], x1 = xr[1], x2 = xr[2], x3 = xr[3];
  float xv[ND] = {x0.x, x0.y, x0.z, x0.w, x1.x, x1.y, x1.z, x1.w,
                  x2.x, x2.y, x2.z, x2.w, x3.x, x3.y, x3.z, x3.w};
#pragma unroll
  for (int q = 0; q < HD; ++q) {
    float acc = 0.f;
#pragma unroll
    for (int j = 0; j < ND; ++j) acc += Wn1[q * ND + j] * xv[j];
    h1[(size_t)n * HD + q] = e1 * acc + agg1p[(size_t)n * HD + q] + bn1[q];
  }
}

__global__ __launch_bounds__(256) void edge_pass2(
    const float* __restrict__ ea, const int* __restrict__ ei,
    const float* __restrict__ hn,
    const float* __restrict__ W2e, const float* __restrict__ b2e,
    const float* __restrict__ Wn2,
    float* __restrict__ agg2s, long E) {
  __shared__ float sW[HD * ED];
  __shared__ float sB[HD];
  __shared__ float sP[HD];
  int tid = threadIdx.x;
  if (tid < HD * ED) sW[tid] = W2e[tid];
  if (tid < HD) sB[tid] = b2e[tid];
  if (tid < HD) sP[tid] = Wn2[tid];
  __syncthreads();
  const float4* ea4 = reinterpret_cast<const float4*>(ea);
  const int* src = ei;
  const int* dst = ei + E;
  long idx = (long)blockIdx.x * blockDim.x + tid;
  long stride = (long)gridDim.x * blockDim.x;
  for (long e = idx; e < E; e += stride) {
    float4 a0 = ea4[2 * e];
    float4 a1 = ea4[2 * e + 1];
    float av[ED] = {a0.x, a0.y, a0.z, a0.w, a1.x, a1.y, a1.z, a1.w};
    int s = src[e];
    int d = dst[e];
    const float* hr = hn + (size_t)s * HD;
    float acc = 0.f;
#pragma unroll
    for (int q = 0; q < HD; ++q) {
      float m = sB[q];
#pragma unroll
      for (int k = 0; k < ED; ++k) m += sW[q * ED + k] * av[k];
      m = fmaxf(m + hr[q], 0.f);
      acc += m * sP[q];
    }
    atomAdd(agg2s + d, acc);
  }
}

__global__ __launch_bounds__(256) void node_pass2(
    const float* __restrict__ hn, const float* __restrict__ agg2s,
    const float* __restrict__ Wn2, const float* __restrict__ bn2,
    const float* __restrict__ eps2p, float* __restrict__ out, int N) {
  int n = blockIdx.x * blockDim.x + threadIdx.x;
  if (n >= N) return;
  float e2 = 1.0f + *eps2p;
  const float* hr = hn + (size_t)n * HD;
  float z = bn2[0] + agg2s[n];
#pragma unroll
  for (int q = 0; q < HD; ++q) z += Wn2[q] * e2 * hr[q];
  out[n] = 1.0f / (1.0f + expf(-z));
}

// ===========================================================================
extern "C" void kernel_launch(void* const* d_in, const int* in_sizes, int n_in,
                              void* d_out, int out_size, void* d_ws, size_t ws_size,
                              hipStream_t stream) {
  const float* x       = (const float*)d_in[0];
  const int*   ei      = (const int*)d_in[1];
  const float* ea      = (const float*)d_in[2];
  const int*   batch   = (const int*)d_in[3];
  const float* eps1    = (const float*)d_in[4];
  const float* W1e     = (const float*)d_in[5];
  const float* b1e     = (const float*)d_in[6];
  const float* Wn1     = (const float*)d_in[7];
  const float* bn1     = (const float*)d_in[8];
  const float* gn_w    = (const float*)d_in[9];
  const float* gn_b    = (const float*)d_in[10];
  const float* gn_ms   = (const float*)d_in[11];
  const float* eps2    = (const float*)d_in[12];
  const float* W2e     = (const float*)d_in[13];
  const float* b2e     = (const float*)d_in[14];
  const float* Wn2     = (const float*)d_in[15];
  const float* bn2     = (const float*)d_in[16];

  const int  N = in_sizes[3];
  const long E = (long)in_sizes[2] / ED;
  const int  NB = (N + BUCKET_NODES - 1) >> BUCKET_SHIFT;
  const size_t NBp = ((size_t)NB + 3) & ~(size_t)3;

  // sort-path workspace (float/int units)
  const size_t recF  = (size_t)E * 12;          // 48B records
  const size_t offsI = (size_t)NBLK * NB;
  const size_t need  = (recF + offsI + 2 * NBp + 10 * (size_t)N + 64) * 4;

  float* out = (float*)d_out;
  const int* srcp = ei;
  const int* dstp = ei + E;

  if (ws_size >= need && NB <= NB_MAX) {
    // ------------------------- SORT PATH -------------------------
    float* ws    = (float*)d_ws;
    float* rec   = ws;
    int*   offs  = (int*)(ws + recF);
    int*   btot  = (int*)(ws + recF + offsI);
    int*   bbase = (int*)(ws + recF + offsI + NBp);
    float* h1    = ws + recF + offsI + 2 * NBp;
    float* hn    = h1 + 5 * (size_t)N;

    const long chunk = (E + NBLK - 1) / NBLK;

    hist_kernel<<<NBLK, 256, 0, stream>>>(dstp, offs, E, NB, chunk);
    scan_blocks<<<NB, 256, 0, stream>>>(offs, btot, NB);
    scanB<<<1, 256, 0, stream>>>(btot, bbase, NB);
    build_scatter<<<NBLK, 256, 0, stream>>>(ea, srcp, dstp, x,
                                            W1e, b1e, Wn1, W2e, b2e,
                                            offs, bbase, rec, E, NB, chunk);
    reduce1<<<NB, 256, 0, stream>>>(rec, bbase, btot, x, Wn1, bn1, eps1, h1, N);
    graphnorm_pass<<<NG, 256, 0, stream>>>(h1, batch, gn_w, gn_b, gn_ms, hn, N);
    reduce2<<<NB, 256, 0, stream>>>(rec, bbase, btot, hn, Wn2, bn2, eps2, out, N);
  } else {
    // ----------------------- FALLBACK PATH -----------------------
    float* ws     = (float*)d_ws;
    float* agg1p  = ws;
    float* agg2s  = ws + (size_t)N * 5;
    float* h1     = ws + (size_t)N * 6;
    float* hn     = ws + (size_t)N * 11;

    hipMemsetAsync(ws, 0, (size_t)N * 6 * sizeof(float), stream);

    const int TB = 256;
    int edge_blocks = 4096;
    int node_blocks = (N + TB - 1) / TB;

    edge_pass1<<<edge_blocks, TB, 0, stream>>>(ea, ei, x, W1e, b1e, Wn1, agg1p, E);
    node_pass1<<<node_blocks, TB, 0, stream>>>(x, agg1p, Wn1, bn1, eps1, h1, N);
    graphnorm_pass<<<NG, TB, 0, stream>>>(h1, batch, gn_w, gn_b, gn_ms, hn, N);
    edge_pass2<<<edge_blocks, TB, 0, stream>>>(ea, ei, hn, W2e, b2e, Wn2, agg2s, E);
    node_pass2<<<node_blocks, TB, 0, stream>>>(hn, agg2s, Wn2, bn2, eps2, out, N);
  }
}